// Round 4
// baseline (603.359 us; speedup 1.0000x reference)
//
#include <hip/hip_runtime.h>
#include <math.h>

// Keep all float arithmetic un-contracted (separate mul/add like the numpy/jax
// f32 reference) so discrete decisions (argmax, top-k order, iou>thr) match.
#pragma clang fp contract(off)

// ---------------- problem constants ----------------
#define BB      8
#define AA      9
#define NCLS    80
#define NTOT    72000      // 57600 + 14400 boxes per image
#define PRE     1000
#define POST    300
#define CAP     4096       // candidate cap per image (expected ~1000-1100)
#define NBINS   65536
#define BCLIP   4.135166556742356f   // log(1000/16)
#define NB0     225        // 14400 groups / 64
#define NB1     57         // ceil(3600 / 64)

__device__ __constant__ float c_sizes[9] = {16.f,32.f,64.f,20.f,40.f,80.f,24.f,48.f,96.f};

__device__ inline unsigned fkey(float s) {
    unsigned u = __float_as_uint(s);
    return (u & 0x80000000u) ? ~u : (u | 0x80000000u);
}
__device__ inline float unfkey(unsigned u) {
    return __uint_as_float((u & 0x80000000u) ? (u ^ 0x80000000u) : ~u);
}

// ---------------- kernel 1: decode + argmax (class-dim split 4 ways) ------------
// Block = 4 waves. Wave c scans classes [20c,20c+20) for 64 float4 cell-groups and
// loads delta channel c. Packed key (fkey<<32)|~cls reproduces first-max tie-break.
// Internal m-layout: m = MBASE + a*HW + hw (coalesced); reference n recomputed later.
template<int HW, int W, int STRIDE, int MBASE>
__device__ inline void decode_impl(
    const float* __restrict__ data, int bid, int b,
    unsigned long long (*skey)[64][4], float4 (*sdel)[64],
    float* __restrict__ boxes, float* __restrict__ scores, float* __restrict__ cls,
    unsigned* __restrict__ hist)
{
    constexpr int Q  = HW / 4;
    constexpr int NG = AA * Q;
    int lane  = threadIdx.x & 63;
    int chunk = threadIdx.x >> 6;
    int g = bid * 64 + lane;
    bool valid = (g < NG);
    int a = g / Q;
    int q = g - a * Q;

    const float* p = data + (size_t)(b * 756 + a * 84) * HW + q * 4;

    float4 dv = make_float4(0.f, 0.f, 0.f, 0.f);
    if (valid) dv = *(const float4*)(p + (size_t)chunk * HW);

    const float* sp = p + (size_t)(4 + chunk * 20) * HW;
    unsigned long long key[4] = {0ULL, 0ULL, 0ULL, 0ULL};

    #pragma unroll
    for (int j0 = 0; j0 < 20; j0 += 4) {
        float4 sv[4];
        #pragma unroll
        for (int u = 0; u < 4; u++)
            sv[u] = valid ? *(const float4*)(sp + (size_t)(j0 + u) * HW)
                          : make_float4(0.f, 0.f, 0.f, 0.f);
        #pragma unroll
        for (int u = 0; u < 4; u++) {
            unsigned inv = ~(unsigned)(chunk * 20 + j0 + u);
            unsigned long long nk;
            nk = ((unsigned long long)fkey(sv[u].x) << 32) | inv; if (nk > key[0]) key[0] = nk;
            nk = ((unsigned long long)fkey(sv[u].y) << 32) | inv; if (nk > key[1]) key[1] = nk;
            nk = ((unsigned long long)fkey(sv[u].z) << 32) | inv; if (nk > key[2]) key[2] = nk;
            nk = ((unsigned long long)fkey(sv[u].w) << 32) | inv; if (nk > key[3]) key[3] = nk;
        }
    }

    #pragma unroll
    for (int k = 0; k < 4; k++) skey[chunk][lane][k] = key[k];
    sdel[chunk][lane] = dv;
    __syncthreads();

    // epilogue: thread e handles cell (group e>>2, sub e&3)
    int e  = threadIdx.x;
    int gl = e >> 2, k = e & 3;
    int g2 = bid * 64 + gl;
    if (g2 >= NG) return;
    int a2 = g2 / Q;
    int q2 = g2 - a2 * Q;

    unsigned long long kk = skey[0][gl][k];
    if (skey[1][gl][k] > kk) kk = skey[1][gl][k];
    if (skey[2][gl][k] > kk) kk = skey[2][gl][k];
    if (skey[3][gl][k] > kk) kk = skey[3][gl][k];
    unsigned uk = (unsigned)(kk >> 32);
    float best = unfkey(uk);
    float clsv = (float)(~(unsigned)kk);

    float dx = ((const float*)&sdel[0][gl])[k];
    float dy = ((const float*)&sdel[1][gl])[k];
    float dw = ((const float*)&sdel[2][gl])[k];
    float dh = ((const float*)&sdel[3][gl])[k];

    float sz = c_sizes[a2];
    int hw0 = q2 * 4 + k;
    int h = hw0 / W;
    int w = hw0 - h * W;
    float cy = (h + 0.5f) * (float)STRIDE;
    float cx = (w + 0.5f) * (float)STRIDE;
    float pcx = dx * sz + cx;
    float pcy = dy * sz + cy;
    float pw  = expf(fminf(dw, BCLIP)) * sz;
    float ph  = expf(fminf(dh, BCLIP)) * sz;
    float x1 = fminf(fmaxf(pcx - 0.5f * pw, 0.f), 640.f);
    float y1 = fminf(fmaxf(pcy - 0.5f * ph, 0.f), 640.f);
    float x2 = fminf(fmaxf(pcx + 0.5f * pw, 0.f), 640.f);
    float y2 = fminf(fmaxf(pcy + 0.5f * ph, 0.f), 640.f);

    int m = MBASE + a2 * HW + hw0;
    size_t o = (size_t)b * NTOT + m;
    ((float4*)boxes)[o] = make_float4(x1, y1, x2, y2);
    scores[o] = best;
    cls[o]    = clsv;
    atomicAdd(&hist[(size_t)b * NBINS + (uk >> 16)], 1u);
}

__global__ __launch_bounds__(256) void k_decode(
    const float* __restrict__ data0, const float* __restrict__ data1,
    float* __restrict__ boxes, float* __restrict__ scores, float* __restrict__ cls,
    unsigned* __restrict__ hist)
{
    __shared__ unsigned long long skey[4][64][4];
    __shared__ float4 sdel[4][64];
    int bx = blockIdx.x, b = blockIdx.y;
    if (bx < NB0)
        decode_impl<6400, 80, 8, 0>(data0, bx, b, skey, sdel, boxes, scores, cls, hist);
    else
        decode_impl<1600, 40, 16, 57600>(data1, bx - NB0, b, skey, sdel, boxes, scores, cls, hist);
}

// ---------------- kernel 2: per-image 16-bit threshold bucket ----------------
__global__ __launch_bounds__(1024) void k_thresh(const unsigned* __restrict__ hist,
                                                 unsigned* __restrict__ T)
{
    __shared__ unsigned S[256];
    __shared__ int Csh;
    __shared__ unsigned cumAbove;
    int b = blockIdx.x, tid = threadIdx.x;
    const unsigned* hb = hist + (size_t)b * NBINS;
    const uint4* hb4 = (const uint4*)hb;

    // coarse: 4 threads per 256-bin coarse bucket, 16 uint4 each
    int c = tid >> 2, part = tid & 3;
    unsigned s = 0;
    #pragma unroll 4
    for (int i = 0; i < 16; i++) {
        uint4 v = hb4[c * 64 + part * 16 + i];
        s += v.x + v.y + v.z + v.w;
    }
    s += __shfl_xor(s, 1);
    s += __shfl_xor(s, 2);
    if (part == 0) S[c] = s;
    __syncthreads();

    for (int off = 1; off < 256; off <<= 1) {   // suffix sum over coarse bins
        unsigned v = 0;
        if (tid < 256) v = S[tid] + ((tid + off < 256) ? S[tid + off] : 0u);
        __syncthreads();
        if (tid < 256) S[tid] = v;
        __syncthreads();
    }
    if (tid < 256 && S[tid] >= (unsigned)PRE && (tid == 255 || S[tid + 1] < (unsigned)PRE)) {
        Csh = tid;
        cumAbove = (tid == 255) ? 0u : S[tid + 1];
    }
    __syncthreads();
    int C = Csh; unsigned ca = cumAbove;
    unsigned f = (tid < 256) ? hb[C * 256 + tid] : 0u;
    __syncthreads();
    if (tid < 256) S[tid] = f;
    __syncthreads();
    for (int off = 1; off < 256; off <<= 1) {
        unsigned v = 0;
        if (tid < 256) v = S[tid] + ((tid + off < 256) ? S[tid + off] : 0u);
        __syncthreads();
        if (tid < 256) S[tid] = v;
        __syncthreads();
    }
    if (tid < 256 && ca + S[tid] >= (unsigned)PRE &&
        (tid == 255 || ca + S[tid + 1] < (unsigned)PRE))
        T[b] = (unsigned)(C * 256 + tid);
}

// ---------------- kernel 3: compact candidates >= threshold bucket ----------------
__global__ __launch_bounds__(256) void k_compact(const float* __restrict__ scores,
                                                 const unsigned* __restrict__ T,
                                                 unsigned* __restrict__ cnt,
                                                 unsigned long long* __restrict__ cand)
{
    int m4 = blockIdx.x * 256 + threadIdx.x;
    int b = blockIdx.y;
    if (m4 >= NTOT / 4) return;
    float sv[4];
    *(float4*)sv = ((const float4*)(scores + (size_t)b * NTOT))[m4];
    unsigned Tb = T[b];
    #pragma unroll
    for (int k = 0; k < 4; k++) {
        unsigned u = fkey(sv[k]);
        if ((u >> 16) >= Tb) {
            int m = m4 * 4 + k;
            int n;
            if (m < 57600) { int a = m / 6400; int hw = m - a * 6400; n = hw * 9 + a; }
            else { int mm = m - 57600; int a = mm / 1600; int hw = mm - a * 1600; n = 57600 + hw * 9 + a; }
            unsigned pos = atomicAdd(&cnt[b], 1u);
            if (pos < CAP)
                cand[(size_t)b * CAP + pos] = ((unsigned long long)u << 32) | (unsigned)(~(unsigned)n);
        }
    }
}

// ---------------- kernel 4: per-image bitonic sort (runtime pow2) + gather ------
__global__ __launch_bounds__(1024) void k_sort(
    const unsigned long long* __restrict__ cand, const unsigned* __restrict__ cnt,
    const float* __restrict__ boxes, const float* __restrict__ scores, const float* __restrict__ cls,
    float* __restrict__ sboxes, float* __restrict__ sscores, float* __restrict__ scls)
{
    __shared__ unsigned long long keys[CAP];
    int b = blockIdx.x, tid = threadIdx.x;
    int c = min((int)cnt[b], CAP);
    int P = 1024;
    while (P < c) P <<= 1;              // 1024 / 2048 / 4096, uniform per block
    for (int i = tid; i < P; i += 1024)
        keys[i] = (i < c) ? cand[(size_t)b * CAP + i] : 0ULL;

    for (int k2 = 2; k2 <= P; k2 <<= 1)
        for (int j = k2 >> 1; j > 0; j >>= 1) {
            __syncthreads();
            for (int i = tid; i < P; i += 1024) {
                int l = i ^ j;
                if (l > i) {
                    unsigned long long x = keys[i], y = keys[l];
                    bool up = ((i & k2) == 0);
                    if ((x > y) == up) { keys[i] = y; keys[l] = x; }
                }
            }
        }
    __syncthreads();

    if (tid < PRE) {
        unsigned long long key = keys[P - 1 - tid];       // descending
        int n = (int)~(unsigned)(key & 0xFFFFFFFFu);
        int m;
        if (n < 57600) { int hw = n / 9; int a = n - hw * 9; m = a * 6400 + hw; }
        else { int n2 = n - 57600; int hw = n2 / 9; int a = n2 - hw * 9; m = 57600 + a * 1600 + hw; }
        size_t src = (size_t)b * NTOT + m;
        ((float4*)sboxes)[b * 1024 + tid] = ((const float4*)boxes)[src];
        sscores[b * 1024 + tid] = scores[src];
        scls[b * 1024 + tid] = cls[src];
    }
}

// ---------------- kernel 5: suppression bitmask (1000 x 1000) ----------------
__global__ __launch_bounds__(1024) void k_mask(const float* __restrict__ sboxes,
                                               const float* __restrict__ sscores,
                                               unsigned long long* __restrict__ mask)
{
    __shared__ float4 bx[64];
    __shared__ float  sl[64];
    int b = blockIdx.y, w = blockIdx.x, tid = threadIdx.x;
    if (tid < 64) {
        int j = w * 64 + tid;
        bx[tid] = ((const float4*)sboxes)[b * 1024 + j];
        sl[tid] = sscores[b * 1024 + j];
    }
    __syncthreads();
    int r = tid;
    unsigned long long* dst = &mask[((size_t)(b * 1024) + r) * 16 + w];
    if (r >= PRE || w * 64 + 63 <= r) { *dst = 0ULL; return; }

    float4 br = ((const float4*)sboxes)[b * 1024 + r];
    float sr = sscores[b * 1024 + r];
    float arear = (br.z - br.x) * (br.w - br.y);
    unsigned long long bits = 0;
    int jend = min(64, PRE - w * 64);
    for (int jj = 0; jj < jend; jj++) {
        int j = w * 64 + jj;
        float4 bj = bx[jj];
        float ix1 = fmaxf(br.x, bj.x), iy1 = fmaxf(br.y, bj.y);
        float ix2 = fminf(br.z, bj.z), iy2 = fminf(br.w, bj.w);
        float iw = fmaxf(ix2 - ix1, 0.f), ih = fmaxf(iy2 - iy1, 0.f);
        float inter = iw * ih;
        float areaj = (bj.z - bj.x) * (bj.w - bj.y);
        float iou = inter / (arear + areaj - inter + 1e-9f);
        if (j > r && iou > 0.5f && sr > sl[jj]) bits |= 1ull << jj;
    }
    *dst = bits;
}

// ---------------- kernel 6: chunked greedy NMS + output (one wave per image) ----
__global__ __launch_bounds__(64) void k_nms(const unsigned long long* __restrict__ mask,
                                            const float* __restrict__ sboxes,
                                            const float* __restrict__ sscores,
                                            const float* __restrict__ scls,
                                            float* __restrict__ out)
{
    int b = blockIdx.x, lane = threadIdx.x;
    const unsigned long long* mrow = mask + (size_t)b * 1024 * 16;

    unsigned long long validw = 0;
    for (int w = 0; w < 16; w++) {
        int r = w * 64 + lane;
        bool v = false;
        if (r < PRE) {
            float sc = sscores[b * 1024 + r];
            float4 bbx = ((const float4*)sboxes)[b * 1024 + r];
            v = (sc >= 0.05f) && (bbx.x < bbx.z) && (bbx.y < bbx.w);
        }
        unsigned long long bal = __ballot(v);
        if (lane == w) validw = bal;
    }

    unsigned long long remv = 0, keepw = 0;

    for (int c = 0; c < 16; c++) {
        const unsigned long long* myrow = mrow + (size_t)(c * 64 + lane) * 16;
        unsigned long long m_cc = myrow[c];
        unsigned long long rw[16];
        rw[0] = 0;
        #pragma unroll
        for (int w = 1; w < 16; w++)
            rw[w] = (w > c) ? myrow[w] : 0ULL;

        unsigned long long cur = __shfl(validw & ~remv, c);
        for (int jj = 0; jj < 64; jj++) {
            if ((cur >> jj) & 1ULL) {
                unsigned long long row = __shfl(m_cc, jj);
                cur &= ~row;
            }
        }
        if (lane == c) keepw = cur;

        bool mykept = ((cur >> lane) & 1ULL) != 0;
        #pragma unroll
        for (int w = 1; w < 16; w++) {
            if (w > c) {
                unsigned long long v = mykept ? rw[w] : 0ULL;
                v |= __shfl_xor(v, 32);
                v |= __shfl_xor(v, 16);
                v |= __shfl_xor(v, 8);
                v |= __shfl_xor(v, 4);
                v |= __shfl_xor(v, 2);
                v |= __shfl_xor(v, 1);
                if (lane == w) remv |= v;
            }
        }
    }

    __shared__ unsigned long long kws[16];
    __shared__ int pfx[17];
    if (lane < 16) kws[lane] = keepw;
    __syncthreads();
    if (lane == 0) {
        int s = 0;
        for (int w = 0; w < 16; w++) { pfx[w] = s; s += __popcll(kws[w]); }
        pfx[16] = s;
    }
    __syncthreads();
    int nk = pfx[16];

    float* ob = out;                       // [8][300][4]
    float* os = out + BB * POST * 4;       // [8][300]
    float* oc = os + BB * POST;            // [8][300]

    for (int r = lane; r < PRE; r += 64) {
        int w = r >> 6;
        unsigned long long kw = kws[w];
        if ((kw >> (r & 63)) & 1ULL) {
            int rank = pfx[w] + __popcll(kw & ((1ULL << (r & 63)) - 1ULL));
            if (rank < POST) {
                ((float4*)ob)[b * POST + rank] = ((const float4*)sboxes)[b * 1024 + r];
                os[b * POST + rank] = sscores[b * 1024 + r];
                oc[b * POST + rank] = scls[b * 1024 + r];
            }
        }
    }
    for (int p = nk + lane; p < POST; p += 64) {
        ((float4*)ob)[b * POST + p] = make_float4(0.f, 0.f, 0.f, 0.f);
        os[b * POST + p] = 0.f;
        oc[b * POST + p] = 0.f;
    }
}

// ---------------- launch ----------------
extern "C" void kernel_launch(void* const* d_in, const int* in_sizes, int n_in,
                              void* d_out, int out_size, void* d_ws, size_t ws_size,
                              hipStream_t stream)
{
    const float* data0 = (const float*)d_in[0];
    const float* data1 = (const float*)d_in[2];
    for (int i = 0; i < n_in; i++) {
        if (in_sizes[i] == 8 * 756 * 6400) data0 = (const float*)d_in[i];
        else if (in_sizes[i] == 8 * 756 * 1600) data1 = (const float*)d_in[i];
    }

    char* ws = (char*)d_ws;
    size_t off = 0;
    auto alloc = [&](size_t bytes) -> char* {
        char* p = ws + off;
        off = (off + bytes + 255) & ~(size_t)255;
        return p;
    };

    float* boxes   = (float*)alloc((size_t)BB * NTOT * 4 * 4);
    float* scores  = (float*)alloc((size_t)BB * NTOT * 4);
    float* cls     = (float*)alloc((size_t)BB * NTOT * 4);
    unsigned* hist = (unsigned*)alloc((size_t)BB * NBINS * 4);
    unsigned* cnt  = (unsigned*)alloc(BB * 4);          // directly after hist (256-aligned)
    unsigned* T    = (unsigned*)alloc(BB * 4);
    unsigned long long* cand = (unsigned long long*)alloc((size_t)BB * CAP * 8);
    float* sboxes  = (float*)alloc((size_t)BB * 1024 * 4 * 4);
    float* sscores = (float*)alloc((size_t)BB * 1024 * 4);
    float* scls    = (float*)alloc((size_t)BB * 1024 * 4);
    unsigned long long* mask = (unsigned long long*)alloc((size_t)BB * 1024 * 16 * 8);

    // zero hist + cnt (contiguous: hist is 2 MB, 256-multiple; cnt follows)
    (void)hipMemsetAsync(hist, 0, (size_t)BB * NBINS * 4 + 256, stream);

    dim3 g0(NB0 + NB1, BB);                 // both branches in one dispatch
    k_decode<<<g0, 256, 0, stream>>>(data0, data1, boxes, scores, cls, hist);

    k_thresh<<<BB, 1024, 0, stream>>>(hist, T);

    dim3 g3((NTOT / 4 + 255) / 256, BB);
    k_compact<<<g3, 256, 0, stream>>>(scores, T, cnt, cand);

    k_sort<<<BB, 1024, 0, stream>>>(cand, cnt, boxes, scores, cls, sboxes, sscores, scls);

    dim3 g5(16, BB);
    k_mask<<<g5, 1024, 0, stream>>>(sboxes, sscores, mask);

    k_nms<<<BB, 64, 0, stream>>>(mask, sboxes, sscores, scls, (float*)d_out);
}